// Round 1
// 646.122 us; speedup vs baseline: 1.0132x; 1.0132x over previous
//
#include <hip/hip_runtime.h>
#include <hip/hip_bf16.h>

// Problem constants
#define TOTAL_NODES 32768   // B*N = 64*512
#define NNODE 512
#define ETOT 524288         // B*E = 64*8192

typedef unsigned short u16;
typedef __attribute__((ext_vector_type(8))) short bf16x8;
typedef __attribute__((ext_vector_type(4))) float f32x4;

union U8 { bf16x8 v; u16 s[8]; uint4 q; };

__device__ __forceinline__ float bf2f(u16 u) {
    union { unsigned int i; float f; } x; x.i = ((unsigned int)u) << 16; return x.f;
}
__device__ __forceinline__ u16 f2bf(float f) {
    union { __hip_bfloat16 h; u16 u; } c; c.h = __float2bfloat16(f); return c.u;
}
__device__ __forceinline__ f32x4 mfma16(bf16x8 a, bf16x8 b, f32x4 c) {
    return __builtin_amdgcn_mfma_f32_16x16x32_bf16(a, b, c, 0, 0, 0);
}

// ---------------------------------------------------------------------------
// histogram: cnt_row[row[e]]++, cnt_col[col[e]]++  (int atomics, L2-resident)
__global__ void hist_kernel(const int* __restrict__ ei, int* __restrict__ cnt_row,
                            int* __restrict__ cnt_col) {
    int e = blockIdx.x * blockDim.x + threadIdx.x;
    if (e < ETOT) {
        atomicAdd(&cnt_row[ei[e]], 1);
        atomicAdd(&cnt_col[ei[ETOT + e]], 1);
    }
}

// exclusive prefix scan over cnt_col[32768] -> offs[32769], cur[32768]
// fused: dinv = rsqrt(cnt_row + 1)
__global__ __launch_bounds__(1024) void scan_kernel(const int* __restrict__ cnt,
                                                    int* __restrict__ offs,
                                                    int* __restrict__ cur,
                                                    const int* __restrict__ cnt_row,
                                                    float* __restrict__ dinv) {
    __shared__ int part[1024];
    const int t = threadIdx.x;
    const int base = t * 32;
    int local[32];
    int s = 0;
#pragma unroll
    for (int i = 0; i < 32; i++) { local[i] = s; s += cnt[base + i]; }
    part[t] = s;
    __syncthreads();
    for (int off = 1; off < 1024; off <<= 1) {
        int v = (t >= off) ? part[t - off] : 0;
        __syncthreads();
        part[t] += v;
        __syncthreads();
    }
    int prefix = (t == 0) ? 0 : part[t - 1];
#pragma unroll
    for (int i = 0; i < 32; i++) {
        int o = prefix + local[i];
        offs[base + i] = o;
        cur[base + i] = o;
    }
    if (t == 1023) offs[32768] = prefix + s;
#pragma unroll
    for (int i = 0; i < 32; i++)
        dinv[base + i] = rsqrtf((float)cnt_row[base + i] + 1.0f);
}

// scatter edge ids into CSR-by-col order
__global__ void scatter_kernel(const int* __restrict__ ei, int* __restrict__ cur,
                               int2* __restrict__ pairs) {
    int e = blockIdx.x * blockDim.x + threadIdx.x;
    if (e < ETOT) {
        int r = ei[e], c = ei[ETOT + e];
        int pos = atomicAdd(&cur[c], 1);
        pairs[pos] = make_int2(r, e);
    }
}

// gather: h[c] = dinv[c] * sum_in(dinv[r]*relu(h0[r]+ee[e])) + relu(h0[c]+root)/deg[c]
// one 128-thread block per destination node; atomic-free, single write.
__global__ __launch_bounds__(128) void gather_kernel(const int2* __restrict__ pairs,
                                                     const int* __restrict__ offs,
                                                     const int* __restrict__ cnt_row,
                                                     const float* __restrict__ dinv,
                                                     const float* __restrict__ h0,
                                                     const float* __restrict__ ee,
                                                     const float* __restrict__ root,
                                                     float* __restrict__ h) {
    const int c = blockIdx.x;
    const int d = threadIdx.x;
    const int s = offs[c], e_end = offs[c + 1];
    float acc = 0.0f;
    int i = s;
    for (; i + 2 <= e_end; i += 2) {
        int2 p0 = pairs[i], p1 = pairs[i + 1];
        float d0 = dinv[p0.x], d1 = dinv[p1.x];
        float v0 = h0[(size_t)p0.x * 128 + d] + ee[(size_t)p0.y * 128 + d];
        float v1 = h0[(size_t)p1.x * 128 + d] + ee[(size_t)p1.y * 128 + d];
        acc += fmaxf(v0, 0.0f) * d0 + fmaxf(v1, 0.0f) * d1;
    }
    for (; i < e_end; i++) {
        int2 p0 = pairs[i];
        float v0 = h0[(size_t)p0.x * 128 + d] + ee[(size_t)p0.y * 128 + d];
        acc += fmaxf(v0, 0.0f) * dinv[p0.x];
    }
    float degc = (float)cnt_row[c] + 1.0f;
    float hv = h0[(size_t)c * 128 + d] + root[d];
    h[(size_t)c * 128 + d] = dinv[c] * acc + fmaxf(hv, 0.0f) / degc;
}

// ---------------------------------------------------------------------------
// Row-tiled GEMM: out[r, c] = in[r, :128] @ W[128, OUTC] (+ bias), fp32.
template <int OUTC>
__global__ __launch_bounds__(256) void gemm_kernel(const float* __restrict__ in,
                                                   const float* __restrict__ W,
                                                   const float* __restrict__ bias,
                                                   float* __restrict__ outp) {
    __shared__ __align__(16) float a_lds[8 * 128];
    const int rb = blockIdx.x * 8;
    const int t = threadIdx.x;
    for (int idx = t; idx < 8 * 128; idx += OUTC)
        a_lds[idx] = in[(size_t)(rb + (idx >> 7)) * 128 + (idx & 127)];
    __syncthreads();

    float acc[8];
    float bv = bias ? bias[t] : 0.0f;
#pragma unroll
    for (int r = 0; r < 8; r++) acc[r] = bv;

    const float4* a4 = (const float4*)a_lds;
    for (int k4 = 0; k4 < 32; k4++) {
        float w0 = W[(k4 * 4 + 0) * OUTC + t];
        float w1 = W[(k4 * 4 + 1) * OUTC + t];
        float w2 = W[(k4 * 4 + 2) * OUTC + t];
        float w3 = W[(k4 * 4 + 3) * OUTC + t];
#pragma unroll
        for (int r = 0; r < 8; r++) {
            float4 a = a4[r * 32 + k4];
            acc[r] = fmaf(a.x, w0, fmaf(a.y, w1, fmaf(a.z, w2, fmaf(a.w, w3, acc[r]))));
        }
    }
#pragma unroll
    for (int r = 0; r < 8; r++) outp[(size_t)(rb + r) * OUTC + t] = acc[r];
}

// ---------------------------------------------------------------------------
// Fused q/kv projection + bf16 prep. One pass over h.
//   t <  128 : q col t       -> qout fp32 (same as old gemm<128>)
//   t <  256 : k col (t-128) -> khi/klo split-bf16, staged in LDS, coalesced write
//   t >= 256 : v col (t-256) -> vT tiled bf16 [bh][node/8][d(32)][node%8], one uint4/thread
// Block = 8 nodes (all in one graph since 512 % 8 == 0); branch is wave-uniform.
__global__ __launch_bounds__(384) void qkv_kernel(const float* __restrict__ in,
                                                  const float* __restrict__ Wq,
                                                  const float* __restrict__ Wkv,
                                                  float* __restrict__ qout,
                                                  u16* __restrict__ khi,
                                                  u16* __restrict__ klo,
                                                  u16* __restrict__ vT) {
    __shared__ __align__(16) float a_lds[8 * 128];
    __shared__ __align__(16) u16 kstage[2][8 * 128];   // [hi/lo][node][col]
    const int rb = blockIdx.x * 8;
    const int t = threadIdx.x;
    for (int idx = t; idx < 8 * 128; idx += 384)
        a_lds[idx] = in[(size_t)(rb + (idx >> 7)) * 128 + (idx & 127)];
    __syncthreads();

    float acc[8];
#pragma unroll
    for (int r = 0; r < 8; r++) acc[r] = 0.0f;

    const float4* a4 = (const float4*)a_lds;
    const bool isq = (t < 128);
    const float* Wp = isq ? (Wq + t) : (Wkv + (t - 128));
    const int ldw = isq ? 128 : 256;
    for (int k4 = 0; k4 < 32; k4++) {
        float w0 = Wp[(size_t)(k4 * 4 + 0) * ldw];
        float w1 = Wp[(size_t)(k4 * 4 + 1) * ldw];
        float w2 = Wp[(size_t)(k4 * 4 + 2) * ldw];
        float w3 = Wp[(size_t)(k4 * 4 + 3) * ldw];
#pragma unroll
        for (int r = 0; r < 8; r++) {
            float4 a = a4[r * 32 + k4];
            acc[r] = fmaf(a.x, w0, fmaf(a.y, w1, fmaf(a.z, w2, fmaf(a.w, w3, acc[r]))));
        }
    }

    const int b = rb >> 9;        // graph id
    const int rbl = rb & 511;     // node offset within graph

    if (t < 128) {
#pragma unroll
        for (int r = 0; r < 8; r++) qout[(size_t)(rb + r) * 128 + t] = acc[r];
    } else if (t < 256) {
        const int c = t - 128;
#pragma unroll
        for (int r = 0; r < 8; r++) {
            u16 hi = f2bf(acc[r]);
            kstage[0][r * 128 + c] = hi;
            kstage[1][r * 128 + c] = f2bf(acc[r] - bf2f(hi));
        }
    } else {
        const int c = t - 256;
        const int h = c >> 5, d = c & 31;
        const int bh = b * 4 + h;
        U8 u;
#pragma unroll
        for (int r = 0; r < 8; r++) u.s[r] = f2bf(acc[r]);
        *(uint4*)(vT + ((size_t)(bh * 64 + (rbl >> 3)) * 32 + d) * 8) = u.q;
    }
    __syncthreads();
    // coalesced khi/klo writes: 128 uint4 each, 512 B contiguous per head
    if (t < 256) {
        const int hl = t >> 7;            // 0 = hi, 1 = lo
        const int u = t & 127;            // uint4 id
        const int h = u >> 5;
        const int j = u & 31;             // n*4 + dq
        const int n = j >> 2, dq = j & 3;
        uint4 val = *(const uint4*)(&kstage[hl][n * 128 + h * 32 + dq * 8]);
        u16* dst = (hl ? klo : khi) + (size_t)(b * 4 + h) * 16384 + (size_t)(rbl + n) * 32 + dq * 8;
        *(uint4*)dst = val;
    }
}

// ---------------------------------------------------------------------------
// MFMA attention. vT now tiled: [bh][node/8][d(32)][node%8].
__global__ __launch_bounds__(256) void attn_mfma_kernel(const float* __restrict__ qbuf,
                                                        const u16* __restrict__ khi,
                                                        const u16* __restrict__ klo,
                                                        const u16* __restrict__ vT,
                                                        float* __restrict__ ao) {
    __shared__ u16 transit[8][16 * 36];
    const int t = threadIdx.x;
    const int w = t >> 6, L = t & 63;
    const int n16 = L & 15, quad = L >> 4;
    const int bh = blockIdx.y, b = bh >> 2, h = bh & 3;
    const int qbase = blockIdx.x * 128 + w * 32;

    bf16x8 qhi[2], qlo[2];
#pragma unroll
    for (int p = 0; p < 2; p++) {
        const float* qp = qbuf + (size_t)(b * 512 + qbase + p * 16 + n16) * 128 + h * 32 + quad * 8;
        U8 uh, ul;
#pragma unroll
        for (int j = 0; j < 8; j++) {
            float f = qp[j] * 0.17677669529663687f;
            u16 hi = f2bf(f);
            uh.s[j] = hi;
            ul.s[j] = f2bf(f - bf2f(hi));
        }
        qhi[p] = uh.v; qlo[p] = ul.v;
    }

    const f32x4 zero = {0.f, 0.f, 0.f, 0.f};

    float m[2][4];
#pragma unroll
    for (int p = 0; p < 2; p++)
#pragma unroll
        for (int r = 0; r < 4; r++) m[p][r] = -1e30f;

    for (int j0 = 0; j0 < 512; j0 += 16) {
        U8 ub; ub.q = *(const uint4*)(khi + (size_t)(bh * 512 + j0 + n16) * 32 + quad * 8);
#pragma unroll
        for (int p = 0; p < 2; p++) {
            f32x4 s = mfma16(qhi[p], ub.v, zero);
#pragma unroll
            for (int r = 0; r < 4; r++) m[p][r] = fmaxf(m[p][r], s[r]);
        }
    }
#pragma unroll
    for (int p = 0; p < 2; p++)
#pragma unroll
        for (int r = 0; r < 4; r++) {
            float mv = m[p][r];
#pragma unroll
            for (int mask = 1; mask < 16; mask <<= 1) mv = fmaxf(mv, __shfl_xor(mv, mask));
            m[p][r] = mv;
        }

    float l[2][4] = {{0.f, 0.f, 0.f, 0.f}, {0.f, 0.f, 0.f, 0.f}};
    f32x4 O[2][2];
#pragma unroll
    for (int p = 0; p < 2; p++)
#pragma unroll
        for (int dt = 0; dt < 2; dt++) O[p][dt] = zero;

    u16* tr[2] = { transit[w * 2 + 0], transit[w * 2 + 1] };

    for (int jb = 0; jb < 512; jb += 32) {
#pragma unroll
        for (int jt = 0; jt < 2; jt++) {
            const int j0 = jb + jt * 16;
            const size_t kidx = (size_t)(bh * 512 + j0 + n16) * 32 + quad * 8;
            U8 uh; uh.q = *(const uint4*)(khi + kidx);
            U8 ul; ul.q = *(const uint4*)(klo + kidx);
#pragma unroll
            for (int p = 0; p < 2; p++) {
                f32x4 s = mfma16(qhi[p], uh.v, zero);
                s = mfma16(qhi[p], ul.v, s);
                s = mfma16(qlo[p], uh.v, s);
#pragma unroll
                for (int r = 0; r < 4; r++) {
                    float pr = __expf(s[r] - m[p][r]);
                    u16 pb = f2bf(pr);
                    l[p][r] += bf2f(pb);
                    tr[p][(quad * 4 + r) * 36 + jt * 16 + n16] = pb;
                }
            }
        }
        bf16x8 A[2];
#pragma unroll
        for (int p = 0; p < 2; p++) {
            const u16* trp = tr[p];
            const int off = n16 * 36 + quad * 8;
            uint2 lo = *(const uint2*)(trp + off);
            uint2 hi2 = *(const uint2*)(trp + off + 4);
            U8 ua; ua.q = make_uint4(lo.x, lo.y, hi2.x, hi2.y);
            A[p] = ua.v;
        }
#pragma unroll
        for (int dt = 0; dt < 2; dt++) {
            U8 uv; uv.q = *(const uint4*)(vT + (size_t)bh * 16384
                                          + (size_t)((jb + quad * 8) >> 3) * 256
                                          + (size_t)(dt * 16 + n16) * 8);
#pragma unroll
            for (int p = 0; p < 2; p++) O[p][dt] = mfma16(A[p], uv.v, O[p][dt]);
        }
    }

#pragma unroll
    for (int p = 0; p < 2; p++)
#pragma unroll
        for (int r = 0; r < 4; r++) {
            float lv = l[p][r];
#pragma unroll
            for (int mask = 1; mask < 16; mask <<= 1) lv += __shfl_xor(lv, mask);
            float inv = 1.0f / lv;
#pragma unroll
            for (int dt = 0; dt < 2; dt++)
                ao[(size_t)(b * 512 + qbase + p * 16 + quad * 4 + r) * 128 + h * 32 + dt * 16 + n16]
                    = O[p][dt][r] * inv;
        }
}

// ---------------------------------------------------------------------------
extern "C" void kernel_launch(void* const* d_in, const int* in_sizes, int n_in,
                              void* d_out, int out_size, void* d_ws, size_t ws_size,
                              hipStream_t stream) {
    const float* x    = (const float*)d_in[0];
    const int*   ei   = (const int*)d_in[1];
    const float* ee   = (const float*)d_in[2];
    // d_in[3] = batch (unused; uniform graphs)
    const float* Wg   = (const float*)d_in[4];
    const float* bg   = (const float*)d_in[5];
    const float* root = (const float*)d_in[6];
    const float* Wq   = (const float*)d_in[7];
    const float* Wkv  = (const float*)d_in[8];
    const float* Wo   = (const float*)d_in[9];
    const float* bo   = (const float*)d_in[10];

    // Workspace layout (67.4 MB known-good):
    //   [0,128K)        cnt_row
    //   [128K,256K)     dinv
    //   [256K,16M+256K) buf1: h0 -> q -> attn_out
    //   next 16M        hbuf: h
    //   next 32M        reg3: CSR scratch (dead after gather) -> khi(8M)+klo(8M)
    char* ws = (char*)d_ws;
    int*   cnt_row = (int*)ws;
    float* dinv    = (float*)(ws + 131072);
    float* buf1    = (float*)(ws + 262144);
    float* hbuf    = buf1 + 4194304;
    char*  reg3    = (char*)(hbuf + 4194304);
    u16*   khi     = (u16*)reg3;                     // written by qkv (after gather)
    u16*   klo     = khi + 4194304;
    u16*   vT      = (u16*)d_out;                    // scratch; overwritten by final gemm
    int*   cnt_col = (int*)reg3;                     // CSR scratch lives in reg3 until gather done
    int*   offs    = cnt_col + 32768;
    int*   cur     = offs + 32769;
    int2*  pairs   = (int2*)(cur + 32768 + 1023);

    hipMemsetAsync(cnt_row, 0, 131072, stream);
    hipMemsetAsync(cnt_col, 0, 131072, stream);

    hist_kernel<<<2048, 256, 0, stream>>>(ei, cnt_row, cnt_col);
    scan_kernel<<<1, 1024, 0, stream>>>(cnt_col, offs, cur, cnt_row, dinv);
    scatter_kernel<<<2048, 256, 0, stream>>>(ei, cur, pairs);

    // h0 = x @ W_gcn + b_gcn
    gemm_kernel<128><<<4096, 128, 0, stream>>>(x, Wg, bg, buf1);

    // h = CSR gather + self term
    gather_kernel<<<32768, 128, 0, stream>>>(pairs, offs, cnt_row, dinv, buf1, ee, root, hbuf);

    // fused: q = h@Wq -> buf1 ; k/v = h@Wkv -> khi/klo/vT (bf16), one pass over h
    qkv_kernel<<<4096, 384, 0, stream>>>(hbuf, Wq, Wkv, buf1, khi, klo, vT);

    // MFMA attention -> buf1 (aliases q; per-block disjoint read/write regions)
    attn_mfma_kernel<<<dim3(4, 256), 256, 0, stream>>>(buf1, khi, klo, vT, buf1);

    // out = attn_out @ Wout + b_out
    gemm_kernel<128><<<4096, 128, 0, stream>>>(buf1, Wo, bo, (float*)d_out);
}

// Round 2
// 608.604 us; speedup vs baseline: 1.0756x; 1.0616x over previous
//
#include <hip/hip_runtime.h>
#include <hip/hip_bf16.h>

// Problem constants
#define TOTAL_NODES 32768   // B*N = 64*512
#define NNODE 512
#define ETOT 524288         // B*E = 64*8192

typedef unsigned short u16;
typedef __attribute__((ext_vector_type(8))) short bf16x8;
typedef __attribute__((ext_vector_type(4))) float f32x4;

union U8 { bf16x8 v; u16 s[8]; uint4 q; };

__device__ __forceinline__ float bf2f(u16 u) {
    union { unsigned int i; float f; } x; x.i = ((unsigned int)u) << 16; return x.f;
}
__device__ __forceinline__ u16 f2bf(float f) {
    union { __hip_bfloat16 h; u16 u; } c; c.h = __float2bfloat16(f); return c.u;
}
__device__ __forceinline__ f32x4 mfma16(bf16x8 a, bf16x8 b, f32x4 c) {
    return __builtin_amdgcn_mfma_f32_16x16x32_bf16(a, b, c, 0, 0, 0);
}

// ---------------------------------------------------------------------------
// histogram: cnt_row[row[e]]++, cnt_col[col[e]]++  (int atomics, L2-resident)
__global__ void hist_kernel(const int* __restrict__ ei, int* __restrict__ cnt_row,
                            int* __restrict__ cnt_col) {
    int e = blockIdx.x * blockDim.x + threadIdx.x;
    if (e < ETOT) {
        atomicAdd(&cnt_row[ei[e]], 1);
        atomicAdd(&cnt_col[ei[ETOT + e]], 1);
    }
}

// exclusive prefix scan over cnt_col[32768] -> offs[32769], cur[32768]
// fused: dinv = rsqrt(cnt_row + 1)
__global__ __launch_bounds__(1024) void scan_kernel(const int* __restrict__ cnt,
                                                    int* __restrict__ offs,
                                                    int* __restrict__ cur,
                                                    const int* __restrict__ cnt_row,
                                                    float* __restrict__ dinv) {
    __shared__ int part[1024];
    const int t = threadIdx.x;
    const int base = t * 32;
    int local[32];
    int s = 0;
#pragma unroll
    for (int i = 0; i < 32; i++) { local[i] = s; s += cnt[base + i]; }
    part[t] = s;
    __syncthreads();
    for (int off = 1; off < 1024; off <<= 1) {
        int v = (t >= off) ? part[t - off] : 0;
        __syncthreads();
        part[t] += v;
        __syncthreads();
    }
    int prefix = (t == 0) ? 0 : part[t - 1];
#pragma unroll
    for (int i = 0; i < 32; i++) {
        int o = prefix + local[i];
        offs[base + i] = o;
        cur[base + i] = o;
    }
    if (t == 1023) offs[32768] = prefix + s;
#pragma unroll
    for (int i = 0; i < 32; i++)
        dinv[base + i] = rsqrtf((float)cnt_row[base + i] + 1.0f);
}

// scatter edge ids into CSR-by-col order
__global__ void scatter_kernel(const int* __restrict__ ei, int* __restrict__ cur,
                               int2* __restrict__ pairs) {
    int e = blockIdx.x * blockDim.x + threadIdx.x;
    if (e < ETOT) {
        int r = ei[e], c = ei[ETOT + e];
        int pos = atomicAdd(&cur[c], 1);
        pairs[pos] = make_int2(r, e);
    }
}

// gather: h[c] = dinv[c] * sum_in(dinv[r]*relu(h0[r]+ee[e])) + relu(h0[c]+root)/deg[c]
__global__ __launch_bounds__(128) void gather_kernel(const int2* __restrict__ pairs,
                                                     const int* __restrict__ offs,
                                                     const int* __restrict__ cnt_row,
                                                     const float* __restrict__ dinv,
                                                     const float* __restrict__ h0,
                                                     const float* __restrict__ ee,
                                                     const float* __restrict__ root,
                                                     float* __restrict__ h) {
    const int c = blockIdx.x;
    const int d = threadIdx.x;
    const int s = offs[c], e_end = offs[c + 1];
    float acc = 0.0f;
    int i = s;
    for (; i + 2 <= e_end; i += 2) {
        int2 p0 = pairs[i], p1 = pairs[i + 1];
        float d0 = dinv[p0.x], d1 = dinv[p1.x];
        float v0 = h0[(size_t)p0.x * 128 + d] + ee[(size_t)p0.y * 128 + d];
        float v1 = h0[(size_t)p1.x * 128 + d] + ee[(size_t)p1.y * 128 + d];
        acc += fmaxf(v0, 0.0f) * d0 + fmaxf(v1, 0.0f) * d1;
    }
    for (; i < e_end; i++) {
        int2 p0 = pairs[i];
        float v0 = h0[(size_t)p0.x * 128 + d] + ee[(size_t)p0.y * 128 + d];
        acc += fmaxf(v0, 0.0f) * dinv[p0.x];
    }
    float degc = (float)cnt_row[c] + 1.0f;
    float hv = h0[(size_t)c * 128 + d] + root[d];
    h[(size_t)c * 128 + d] = dinv[c] * acc + fmaxf(hv, 0.0f) / degc;
}

// ---------------------------------------------------------------------------
// W prep: transpose + split-bf16 all four weight matrices into B-fragment layout.
// wt arena (u16 offsets):
//   WgT hi @0       lo @16384
//   WqT hi @32768   lo @49152
//   WkvT hi @65536  lo @98304     (256 rows)
//   WoT hi @131072  lo @147456
// WT[c][k] at row-major [outc][128]; fragment load = uint4 at (c)*128 + kt*32 + quad*8.
__global__ __launch_bounds__(256) void wprep_kernel(const float* __restrict__ Wg,
                                                    const float* __restrict__ Wq,
                                                    const float* __restrict__ Wkv,
                                                    const float* __restrict__ Wo,
                                                    u16* __restrict__ wt) {
    int idx = blockIdx.x * 256 + threadIdx.x;   // 0..81919
    const float* W; int outc; int local; u16* hi; u16* lo;
    if (idx < 16384)      { W = Wg;  outc = 128; local = idx;         hi = wt;          lo = wt + 16384; }
    else if (idx < 32768) { W = Wq;  outc = 128; local = idx - 16384; hi = wt + 32768;  lo = wt + 49152; }
    else if (idx < 65536) { W = Wkv; outc = 256; local = idx - 32768; hi = wt + 65536;  lo = wt + 98304; }
    else                  { W = Wo;  outc = 128; local = idx - 65536; hi = wt + 131072; lo = wt + 147456; }
    int c = local >> 7, k = local & 127;
    float f = W[(size_t)k * outc + c];
    u16 h = f2bf(f);
    hi[local] = h;
    lo[local] = f2bf(f - bf2f(h));
}

// ---------------------------------------------------------------------------
// MFMA GEMM: out[32768][128] = in[32768][128] @ W (WT hi/lo fragments) + bias.
// 64 rows/block, 4 waves (16 rows each), hi/lo split => 3 mfma per (ct,kt).
__global__ __launch_bounds__(256) void mgemm_kernel(const float* __restrict__ in,
                                                    const u16* __restrict__ wthi,
                                                    const u16* __restrict__ wtlo,
                                                    const float* __restrict__ bias,
                                                    float* __restrict__ outp) {
    __shared__ __align__(16) u16 ahi[64 * 136];   // +8 u16 pad: row stride 272B -> 2-way bank alias (free)
    __shared__ __align__(16) u16 alo[64 * 136];
    const int t = threadIdx.x;
    const int rb = blockIdx.x * 64;
    for (int i = t; i < 8192; i += 256) {
        int r = i >> 7, k = i & 127;
        float f = in[(size_t)(rb + r) * 128 + k];
        u16 h = f2bf(f);
        ahi[r * 136 + k] = h;
        alo[r * 136 + k] = f2bf(f - bf2f(h));
    }
    __syncthreads();
    const int w = t >> 6, L = t & 63, n16 = L & 15, quad = L >> 4;
    const int row0 = w * 16;
    bf16x8 Ah[4], Al[4];
#pragma unroll
    for (int kt = 0; kt < 4; kt++) {
        Ah[kt] = *(const bf16x8*)(ahi + (row0 + n16) * 136 + kt * 32 + quad * 8);
        Al[kt] = *(const bf16x8*)(alo + (row0 + n16) * 136 + kt * 32 + quad * 8);
    }
    const f32x4 zero = {0.f, 0.f, 0.f, 0.f};
#pragma unroll
    for (int ct = 0; ct < 8; ct++) {
        f32x4 acc = zero;
#pragma unroll
        for (int kt = 0; kt < 4; kt++) {
            U8 bh_, bl_;
            bh_.q = *(const uint4*)(wthi + (ct * 16 + n16) * 128 + kt * 32 + quad * 8);
            bl_.q = *(const uint4*)(wtlo + (ct * 16 + n16) * 128 + kt * 32 + quad * 8);
            acc = mfma16(Ah[kt], bh_.v, acc);
            acc = mfma16(Ah[kt], bl_.v, acc);
            acc = mfma16(Al[kt], bh_.v, acc);
        }
        float bv = bias ? bias[ct * 16 + n16] : 0.0f;
#pragma unroll
        for (int r = 0; r < 4; r++)
            outp[(size_t)(rb + row0 + quad * 4 + r) * 128 + ct * 16 + n16] = acc[r] + bv;
    }
}

// ---------------------------------------------------------------------------
// Fused q/kv projection via MFMA. One pass over h; emits q fp32, khi/klo split-bf16,
// vT tiled bf16 [bh][n>>3][d(32)][n&7] (exact layout attn reads).
__global__ __launch_bounds__(256) void qkv_mfma_kernel(const float* __restrict__ in,
                                                       const u16* __restrict__ wt,
                                                       float* __restrict__ qout,
                                                       u16* __restrict__ khi,
                                                       u16* __restrict__ klo,
                                                       u16* __restrict__ vT) {
    __shared__ __align__(16) u16 ahi[64 * 136];
    __shared__ __align__(16) u16 alo[64 * 136];
    const int t = threadIdx.x;
    const int rb = blockIdx.x * 64;
    for (int i = t; i < 8192; i += 256) {
        int r = i >> 7, k = i & 127;
        float f = in[(size_t)(rb + r) * 128 + k];
        u16 h = f2bf(f);
        ahi[r * 136 + k] = h;
        alo[r * 136 + k] = f2bf(f - bf2f(h));
    }
    __syncthreads();
    const int w = t >> 6, L = t & 63, n16 = L & 15, quad = L >> 4;
    const int row0 = w * 16;
    const int b = rb >> 9, rbl = rb & 511;
    bf16x8 Ah[4], Al[4];
#pragma unroll
    for (int kt = 0; kt < 4; kt++) {
        Ah[kt] = *(const bf16x8*)(ahi + (row0 + n16) * 136 + kt * 32 + quad * 8);
        Al[kt] = *(const bf16x8*)(alo + (row0 + n16) * 136 + kt * 32 + quad * 8);
    }
    const f32x4 zero = {0.f, 0.f, 0.f, 0.f};
    const u16* WqT_hi  = wt + 32768;
    const u16* WqT_lo  = wt + 49152;
    const u16* WkvT_hi = wt + 65536;
    const u16* WkvT_lo = wt + 98304;

    // ---- Q: kv-independent, fp32 out ----
#pragma unroll
    for (int ct = 0; ct < 8; ct++) {
        f32x4 acc = zero;
#pragma unroll
        for (int kt = 0; kt < 4; kt++) {
            U8 bh_, bl_;
            bh_.q = *(const uint4*)(WqT_hi + (ct * 16 + n16) * 128 + kt * 32 + quad * 8);
            bl_.q = *(const uint4*)(WqT_lo + (ct * 16 + n16) * 128 + kt * 32 + quad * 8);
            acc = mfma16(Ah[kt], bh_.v, acc);
            acc = mfma16(Ah[kt], bl_.v, acc);
            acc = mfma16(Al[kt], bh_.v, acc);
        }
#pragma unroll
        for (int r = 0; r < 4; r++)
            qout[(size_t)(rb + row0 + quad * 4 + r) * 128 + ct * 16 + n16] = acc[r];
    }

    // ---- K: kv cols 0..127 -> khi/klo [bh][node][32] ----
#pragma unroll
    for (int ct = 0; ct < 8; ct++) {
        f32x4 acc = zero;
#pragma unroll
        for (int kt = 0; kt < 4; kt++) {
            U8 bh_, bl_;
            bh_.q = *(const uint4*)(WkvT_hi + (ct * 16 + n16) * 128 + kt * 32 + quad * 8);
            bl_.q = *(const uint4*)(WkvT_lo + (ct * 16 + n16) * 128 + kt * 32 + quad * 8);
            acc = mfma16(Ah[kt], bh_.v, acc);
            acc = mfma16(Ah[kt], bl_.v, acc);
            acc = mfma16(Al[kt], bh_.v, acc);
        }
        const int c = ct * 16 + n16, hh = c >> 5, d = c & 31;
        const size_t base = ((size_t)(b * 4 + hh) * 512 + (rbl + row0 + quad * 4)) * 32 + d;
#pragma unroll
        for (int r = 0; r < 4; r++) {
            u16 hv = f2bf(acc[r]);
            khi[base + (size_t)r * 32] = hv;
            klo[base + (size_t)r * 32] = f2bf(acc[r] - bf2f(hv));
        }
    }

    // ---- V: kv cols 128..255 -> vT tiled [bh][n>>3][d][n&7] ----
#pragma unroll
    for (int ct = 0; ct < 8; ct++) {
        f32x4 acc = zero;
#pragma unroll
        for (int kt = 0; kt < 4; kt++) {
            U8 bh_, bl_;
            bh_.q = *(const uint4*)(WkvT_hi + (128 + ct * 16 + n16) * 128 + kt * 32 + quad * 8);
            bl_.q = *(const uint4*)(WkvT_lo + (128 + ct * 16 + n16) * 128 + kt * 32 + quad * 8);
            acc = mfma16(Ah[kt], bh_.v, acc);
            acc = mfma16(Ah[kt], bl_.v, acc);
            acc = mfma16(Al[kt], bh_.v, acc);
        }
        const int c = ct * 16 + n16, hh = c >> 5, d = c & 31;
        const int n0 = rbl + row0 + quad * 4;
        unsigned int w0 = (unsigned int)f2bf(acc[0]) | ((unsigned int)f2bf(acc[1]) << 16);
        unsigned int w1 = (unsigned int)f2bf(acc[2]) | ((unsigned int)f2bf(acc[3]) << 16);
        uint2 val = make_uint2(w0, w1);
        *(uint2*)(vT + (size_t)(b * 4 + hh) * 16384 + (size_t)(n0 >> 3) * 256 + d * 8 + (n0 & 7)) = val;
    }
}

// ---------------------------------------------------------------------------
// MFMA attention. vT tiled: [bh][node/8][d(32)][node%8]. (unchanged)
__global__ __launch_bounds__(256) void attn_mfma_kernel(const float* __restrict__ qbuf,
                                                        const u16* __restrict__ khi,
                                                        const u16* __restrict__ klo,
                                                        const u16* __restrict__ vT,
                                                        float* __restrict__ ao) {
    __shared__ u16 transit[8][16 * 36];
    const int t = threadIdx.x;
    const int w = t >> 6, L = t & 63;
    const int n16 = L & 15, quad = L >> 4;
    const int bh = blockIdx.y, b = bh >> 2, h = bh & 3;
    const int qbase = blockIdx.x * 128 + w * 32;

    bf16x8 qhi[2], qlo[2];
#pragma unroll
    for (int p = 0; p < 2; p++) {
        const float* qp = qbuf + (size_t)(b * 512 + qbase + p * 16 + n16) * 128 + h * 32 + quad * 8;
        U8 uh, ul;
#pragma unroll
        for (int j = 0; j < 8; j++) {
            float f = qp[j] * 0.17677669529663687f;
            u16 hi = f2bf(f);
            uh.s[j] = hi;
            ul.s[j] = f2bf(f - bf2f(hi));
        }
        qhi[p] = uh.v; qlo[p] = ul.v;
    }

    const f32x4 zero = {0.f, 0.f, 0.f, 0.f};

    float m[2][4];
#pragma unroll
    for (int p = 0; p < 2; p++)
#pragma unroll
        for (int r = 0; r < 4; r++) m[p][r] = -1e30f;

    for (int j0 = 0; j0 < 512; j0 += 16) {
        U8 ub; ub.q = *(const uint4*)(khi + (size_t)(bh * 512 + j0 + n16) * 32 + quad * 8);
#pragma unroll
        for (int p = 0; p < 2; p++) {
            f32x4 s = mfma16(qhi[p], ub.v, zero);
#pragma unroll
            for (int r = 0; r < 4; r++) m[p][r] = fmaxf(m[p][r], s[r]);
        }
    }
#pragma unroll
    for (int p = 0; p < 2; p++)
#pragma unroll
        for (int r = 0; r < 4; r++) {
            float mv = m[p][r];
#pragma unroll
            for (int mask = 1; mask < 16; mask <<= 1) mv = fmaxf(mv, __shfl_xor(mv, mask));
            m[p][r] = mv;
        }

    float l[2][4] = {{0.f, 0.f, 0.f, 0.f}, {0.f, 0.f, 0.f, 0.f}};
    f32x4 O[2][2];
#pragma unroll
    for (int p = 0; p < 2; p++)
#pragma unroll
        for (int dt = 0; dt < 2; dt++) O[p][dt] = zero;

    u16* tr[2] = { transit[w * 2 + 0], transit[w * 2 + 1] };

    for (int jb = 0; jb < 512; jb += 32) {
#pragma unroll
        for (int jt = 0; jt < 2; jt++) {
            const int j0 = jb + jt * 16;
            const size_t kidx = (size_t)(bh * 512 + j0 + n16) * 32 + quad * 8;
            U8 uh; uh.q = *(const uint4*)(khi + kidx);
            U8 ul; ul.q = *(const uint4*)(klo + kidx);
#pragma unroll
            for (int p = 0; p < 2; p++) {
                f32x4 s = mfma16(qhi[p], uh.v, zero);
                s = mfma16(qhi[p], ul.v, s);
                s = mfma16(qlo[p], uh.v, s);
#pragma unroll
                for (int r = 0; r < 4; r++) {
                    float pr = __expf(s[r] - m[p][r]);
                    u16 pb = f2bf(pr);
                    l[p][r] += bf2f(pb);
                    tr[p][(quad * 4 + r) * 36 + jt * 16 + n16] = pb;
                }
            }
        }
        bf16x8 A[2];
#pragma unroll
        for (int p = 0; p < 2; p++) {
            const u16* trp = tr[p];
            const int off = n16 * 36 + quad * 8;
            uint2 lo = *(const uint2*)(trp + off);
            uint2 hi2 = *(const uint2*)(trp + off + 4);
            U8 ua; ua.q = make_uint4(lo.x, lo.y, hi2.x, hi2.y);
            A[p] = ua.v;
        }
#pragma unroll
        for (int dt = 0; dt < 2; dt++) {
            U8 uv; uv.q = *(const uint4*)(vT + (size_t)bh * 16384
                                          + (size_t)((jb + quad * 8) >> 3) * 256
                                          + (size_t)(dt * 16 + n16) * 8);
#pragma unroll
            for (int p = 0; p < 2; p++) O[p][dt] = mfma16(A[p], uv.v, O[p][dt]);
        }
    }

#pragma unroll
    for (int p = 0; p < 2; p++)
#pragma unroll
        for (int r = 0; r < 4; r++) {
            float lv = l[p][r];
#pragma unroll
            for (int mask = 1; mask < 16; mask <<= 1) lv += __shfl_xor(lv, mask);
            float inv = 1.0f / lv;
#pragma unroll
            for (int dt = 0; dt < 2; dt++)
                ao[(size_t)(b * 512 + qbase + p * 16 + quad * 4 + r) * 128 + h * 32 + dt * 16 + n16]
                    = O[p][dt][r] * inv;
        }
}

// ---------------------------------------------------------------------------
extern "C" void kernel_launch(void* const* d_in, const int* in_sizes, int n_in,
                              void* d_out, int out_size, void* d_ws, size_t ws_size,
                              hipStream_t stream) {
    const float* x    = (const float*)d_in[0];
    const int*   ei   = (const int*)d_in[1];
    const float* ee   = (const float*)d_in[2];
    // d_in[3] = batch (unused; uniform graphs)
    const float* Wg   = (const float*)d_in[4];
    const float* bg   = (const float*)d_in[5];
    const float* root = (const float*)d_in[6];
    const float* Wq   = (const float*)d_in[7];
    const float* Wkv  = (const float*)d_in[8];
    const float* Wo   = (const float*)d_in[9];
    const float* bo   = (const float*)d_in[10];

    // Workspace layout (67.4 MB known-good):
    //   [0,128K)        cnt_row
    //   [128K,256K)     dinv
    //   [256K,16M+256K) buf1: h0 -> q -> attn_out
    //   next 16M        hbuf: h
    //   next 32M        reg3: CSR scratch (first 4.6M, dead after gather) -> khi(8M)+klo(8M);
    //                   WT arena (320K) parked at reg3+16M (never overlaps either user)
    char* ws = (char*)d_ws;
    int*   cnt_row = (int*)ws;
    float* dinv    = (float*)(ws + 131072);
    float* buf1    = (float*)(ws + 262144);
    float* hbuf    = buf1 + 4194304;
    char*  reg3    = (char*)(hbuf + 4194304);
    u16*   khi     = (u16*)reg3;                     // written by qkv (after gather)
    u16*   klo     = khi + 4194304;
    u16*   wt      = (u16*)(reg3 + 16777216);        // 320 KB WT hi/lo arena
    u16*   vT      = (u16*)d_out;                    // scratch; overwritten by final gemm
    int*   cnt_col = (int*)reg3;                     // CSR scratch lives in reg3 until gather done
    int*   offs    = cnt_col + 32768;
    int*   cur     = offs + 32769;
    int2*  pairs   = (int2*)(cur + 32768 + 1023);

    hipMemsetAsync(cnt_row, 0, 131072, stream);
    hipMemsetAsync(cnt_col, 0, 131072, stream);

    wprep_kernel<<<320, 256, 0, stream>>>(Wg, Wq, Wkv, Wo, wt);

    hist_kernel<<<2048, 256, 0, stream>>>(ei, cnt_row, cnt_col);
    scan_kernel<<<1, 1024, 0, stream>>>(cnt_col, offs, cur, cnt_row, dinv);
    scatter_kernel<<<2048, 256, 0, stream>>>(ei, cur, pairs);

    // h0 = x @ W_gcn + b_gcn   (MFMA split-bf16)
    mgemm_kernel<<<512, 256, 0, stream>>>(x, wt, wt + 16384, bg, buf1);

    // h = CSR gather + self term
    gather_kernel<<<32768, 128, 0, stream>>>(pairs, offs, cnt_row, dinv, buf1, ee, root, hbuf);

    // fused MFMA: q = h@Wq -> buf1 ; k/v = h@Wkv -> khi/klo/vT (bf16)
    qkv_mfma_kernel<<<512, 256, 0, stream>>>(hbuf, wt, buf1, khi, klo, vT);

    // MFMA attention -> buf1 (aliases q; per-block disjoint read/write regions)
    attn_mfma_kernel<<<dim3(4, 256), 256, 0, stream>>>(buf1, khi, klo, vT, buf1);

    // out = attn_out @ Wout + b_out   (MFMA split-bf16)
    mgemm_kernel<<<512, 256, 0, stream>>>(buf1, wt + 131072, wt + 147456, bo, (float*)d_out);
}

// Round 3
// 554.522 us; speedup vs baseline: 1.1805x; 1.0975x over previous
//
#include <hip/hip_runtime.h>
#include <hip/hip_bf16.h>

// Problem constants
#define TOTAL_NODES 32768   // B*N = 64*512
#define NNODE 512
#define ETOT 524288         // B*E = 64*8192

typedef unsigned short u16;
typedef __attribute__((ext_vector_type(8))) short bf16x8;
typedef __attribute__((ext_vector_type(4))) float f32x4;

union U8 { bf16x8 v; u16 s[8]; uint4 q; };

__device__ __forceinline__ float bf2f(u16 u) {
    union { unsigned int i; float f; } x; x.i = ((unsigned int)u) << 16; return x.f;
}
__device__ __forceinline__ u16 f2bf(float f) {
    union { __hip_bfloat16 h; u16 u; } c; c.h = __float2bfloat16(f); return c.u;
}
__device__ __forceinline__ f32x4 mfma16(bf16x8 a, bf16x8 b, f32x4 c) {
    return __builtin_amdgcn_mfma_f32_16x16x32_bf16(a, b, c, 0, 0, 0);
}

// ---------------------------------------------------------------------------
// setup: blocks 0..63  = per-graph CSR counting sort entirely in LDS
//        blocks 64..127 = weight transpose + split-bf16 (wt arena)
// Replaces hist + scan + scatter + dinv + wprep + 2 memsets (5 dispatches + 2 fills).
// Edges are guaranteed within-graph: graph b owns edges [b*8192,(b+1)*8192) and
// nodes [b*512,(b+1)*512); node_local = node_global & 511.
__global__ __launch_bounds__(512) void setup_kernel(const int* __restrict__ ei,
                                                    const float* __restrict__ Wg,
                                                    const float* __restrict__ Wq,
                                                    const float* __restrict__ Wkv,
                                                    const float* __restrict__ Wo,
                                                    u16* __restrict__ wt,
                                                    float* __restrict__ dinv,
                                                    float* __restrict__ degf,
                                                    int* __restrict__ offs,
                                                    int2* __restrict__ pairs) {
    const int blk = blockIdx.x;
    const int t = threadIdx.x;
    if (blk >= 64) {
        // WT arena (u16 offsets): WgT hi@0 lo@16384 | WqT hi@32768 lo@49152
        //                         WkvT hi@65536 lo@98304 (256 rows) | WoT hi@131072 lo@147456
        for (int idx = (blk - 64) * 512 + t; idx < 81920; idx += 64 * 512) {
            const float* W; int outc; int local; u16* hi; u16* lo;
            if (idx < 16384)      { W = Wg;  outc = 128; local = idx;         hi = wt;          lo = wt + 16384; }
            else if (idx < 32768) { W = Wq;  outc = 128; local = idx - 16384; hi = wt + 32768;  lo = wt + 49152; }
            else if (idx < 65536) { W = Wkv; outc = 256; local = idx - 32768; hi = wt + 65536;  lo = wt + 98304; }
            else                  { W = Wo;  outc = 128; local = idx - 65536; hi = wt + 131072; lo = wt + 147456; }
            int c = local >> 7, k = local & 127;
            float f = W[(size_t)k * outc + c];
            u16 h = f2bf(f);
            hi[local] = h;
            lo[local] = f2bf(f - bf2f(h));
        }
        return;
    }
    __shared__ int cnt_row[512], cnt_col[512], sc[512], cur[512];
    cnt_row[t] = 0;
    cnt_col[t] = 0;
    __syncthreads();
    const int goff = blk * 8192;       // first edge of this graph
    int r[16], c[16];
#pragma unroll
    for (int i = 0; i < 16; i++) {
        int e = t + i * 512;
        r[i] = ei[goff + e];           // global node id
        c[i] = ei[ETOT + goff + e];
        atomicAdd(&cnt_row[r[i] & 511], 1);
        atomicAdd(&cnt_col[c[i] & 511], 1);
    }
    __syncthreads();
    float dg = (float)cnt_row[t] + 1.0f;
    degf[blk * 512 + t] = dg;
    dinv[blk * 512 + t] = rsqrtf(dg);
    sc[t] = cnt_col[t];
    __syncthreads();
    for (int off = 1; off < 512; off <<= 1) {
        int v = (t >= off) ? sc[t - off] : 0;
        __syncthreads();
        sc[t] += v;
        __syncthreads();
    }
    int excl = sc[t] - cnt_col[t];     // exclusive prefix within graph
    offs[blk * 512 + t] = goff + excl;
    cur[t] = excl;
    if (blk == 63 && t == 511) offs[32768] = ETOT;
    __syncthreads();
#pragma unroll
    for (int i = 0; i < 16; i++) {
        int e = t + i * 512;
        int pos = atomicAdd(&cur[c[i] & 511], 1);
        pairs[goff + pos] = make_int2(r[i], goff + e);
    }
}

// ---------------------------------------------------------------------------
// gather: h[c] = dinv[c] * sum_in(dinv[r]*relu(h0[r]+ee[e])) + relu(h0[c]+root)/deg[c]
__global__ __launch_bounds__(128) void gather_kernel(const int2* __restrict__ pairs,
                                                     const int* __restrict__ offs,
                                                     const float* __restrict__ degf,
                                                     const float* __restrict__ dinv,
                                                     const float* __restrict__ h0,
                                                     const float* __restrict__ ee,
                                                     const float* __restrict__ root,
                                                     float* __restrict__ h) {
    const int c = blockIdx.x;
    const int d = threadIdx.x;
    const int s = offs[c], e_end = offs[c + 1];
    float acc = 0.0f;
    int i = s;
    for (; i + 2 <= e_end; i += 2) {
        int2 p0 = pairs[i], p1 = pairs[i + 1];
        float d0 = dinv[p0.x], d1 = dinv[p1.x];
        float v0 = h0[(size_t)p0.x * 128 + d] + ee[(size_t)p0.y * 128 + d];
        float v1 = h0[(size_t)p1.x * 128 + d] + ee[(size_t)p1.y * 128 + d];
        acc += fmaxf(v0, 0.0f) * d0 + fmaxf(v1, 0.0f) * d1;
    }
    for (; i < e_end; i++) {
        int2 p0 = pairs[i];
        float v0 = h0[(size_t)p0.x * 128 + d] + ee[(size_t)p0.y * 128 + d];
        acc += fmaxf(v0, 0.0f) * dinv[p0.x];
    }
    float hv = h0[(size_t)c * 128 + d] + root[d];
    h[(size_t)c * 128 + d] = dinv[c] * acc + fmaxf(hv, 0.0f) / degf[c];
}

// ---------------------------------------------------------------------------
// MFMA GEMM: out[32768][128] = in[32768][128] @ W (WT hi/lo fragments) + bias.
// 64 rows/block, 4 waves (16 rows each), hi/lo split => 3 mfma per (ct,kt).
__global__ __launch_bounds__(256) void mgemm_kernel(const float* __restrict__ in,
                                                    const u16* __restrict__ wthi,
                                                    const u16* __restrict__ wtlo,
                                                    const float* __restrict__ bias,
                                                    float* __restrict__ outp) {
    __shared__ __align__(16) u16 ahi[64 * 136];   // +8 u16 pad: row stride 272B -> 2-way bank alias (free)
    __shared__ __align__(16) u16 alo[64 * 136];
    const int t = threadIdx.x;
    const int rb = blockIdx.x * 64;
    for (int i = t; i < 8192; i += 256) {
        int r = i >> 7, k = i & 127;
        float f = in[(size_t)(rb + r) * 128 + k];
        u16 h = f2bf(f);
        ahi[r * 136 + k] = h;
        alo[r * 136 + k] = f2bf(f - bf2f(h));
    }
    __syncthreads();
    const int w = t >> 6, L = t & 63, n16 = L & 15, quad = L >> 4;
    const int row0 = w * 16;
    bf16x8 Ah[4], Al[4];
#pragma unroll
    for (int kt = 0; kt < 4; kt++) {
        Ah[kt] = *(const bf16x8*)(ahi + (row0 + n16) * 136 + kt * 32 + quad * 8);
        Al[kt] = *(const bf16x8*)(alo + (row0 + n16) * 136 + kt * 32 + quad * 8);
    }
    const f32x4 zero = {0.f, 0.f, 0.f, 0.f};
#pragma unroll
    for (int ct = 0; ct < 8; ct++) {
        f32x4 acc = zero;
#pragma unroll
        for (int kt = 0; kt < 4; kt++) {
            U8 bh_, bl_;
            bh_.q = *(const uint4*)(wthi + (ct * 16 + n16) * 128 + kt * 32 + quad * 8);
            bl_.q = *(const uint4*)(wtlo + (ct * 16 + n16) * 128 + kt * 32 + quad * 8);
            acc = mfma16(Ah[kt], bh_.v, acc);
            acc = mfma16(Ah[kt], bl_.v, acc);
            acc = mfma16(Al[kt], bh_.v, acc);
        }
        float bv = bias ? bias[ct * 16 + n16] : 0.0f;
#pragma unroll
        for (int r = 0; r < 4; r++)
            outp[(size_t)(rb + row0 + quad * 4 + r) * 128 + ct * 16 + n16] = acc[r] + bv;
    }
}

// ---------------------------------------------------------------------------
// Fused q/kv projection via MFMA. One pass over h; emits q fp32, khi/klo split-bf16,
// vT tiled bf16 [bh][n>>3][d(32)][n&7] (exact layout attn reads).
__global__ __launch_bounds__(256) void qkv_mfma_kernel(const float* __restrict__ in,
                                                       const u16* __restrict__ wt,
                                                       float* __restrict__ qout,
                                                       u16* __restrict__ khi,
                                                       u16* __restrict__ klo,
                                                       u16* __restrict__ vT) {
    __shared__ __align__(16) u16 ahi[64 * 136];
    __shared__ __align__(16) u16 alo[64 * 136];
    const int t = threadIdx.x;
    const int rb = blockIdx.x * 64;
    for (int i = t; i < 8192; i += 256) {
        int r = i >> 7, k = i & 127;
        float f = in[(size_t)(rb + r) * 128 + k];
        u16 h = f2bf(f);
        ahi[r * 136 + k] = h;
        alo[r * 136 + k] = f2bf(f - bf2f(h));
    }
    __syncthreads();
    const int w = t >> 6, L = t & 63, n16 = L & 15, quad = L >> 4;
    const int row0 = w * 16;
    const int b = rb >> 9, rbl = rb & 511;
    bf16x8 Ah[4], Al[4];
#pragma unroll
    for (int kt = 0; kt < 4; kt++) {
        Ah[kt] = *(const bf16x8*)(ahi + (row0 + n16) * 136 + kt * 32 + quad * 8);
        Al[kt] = *(const bf16x8*)(alo + (row0 + n16) * 136 + kt * 32 + quad * 8);
    }
    const f32x4 zero = {0.f, 0.f, 0.f, 0.f};
    const u16* WqT_hi  = wt + 32768;
    const u16* WqT_lo  = wt + 49152;
    const u16* WkvT_hi = wt + 65536;
    const u16* WkvT_lo = wt + 98304;

    // ---- Q: fp32 out ----
#pragma unroll
    for (int ct = 0; ct < 8; ct++) {
        f32x4 acc = zero;
#pragma unroll
        for (int kt = 0; kt < 4; kt++) {
            U8 bh_, bl_;
            bh_.q = *(const uint4*)(WqT_hi + (ct * 16 + n16) * 128 + kt * 32 + quad * 8);
            bl_.q = *(const uint4*)(WqT_lo + (ct * 16 + n16) * 128 + kt * 32 + quad * 8);
            acc = mfma16(Ah[kt], bh_.v, acc);
            acc = mfma16(Ah[kt], bl_.v, acc);
            acc = mfma16(Al[kt], bh_.v, acc);
        }
#pragma unroll
        for (int r = 0; r < 4; r++)
            qout[(size_t)(rb + row0 + quad * 4 + r) * 128 + ct * 16 + n16] = acc[r];
    }

    // ---- K: kv cols 0..127 -> khi/klo [bh][node][32] ----
#pragma unroll
    for (int ct = 0; ct < 8; ct++) {
        f32x4 acc = zero;
#pragma unroll
        for (int kt = 0; kt < 4; kt++) {
            U8 bh_, bl_;
            bh_.q = *(const uint4*)(WkvT_hi + (ct * 16 + n16) * 128 + kt * 32 + quad * 8);
            bl_.q = *(const uint4*)(WkvT_lo + (ct * 16 + n16) * 128 + kt * 32 + quad * 8);
            acc = mfma16(Ah[kt], bh_.v, acc);
            acc = mfma16(Ah[kt], bl_.v, acc);
            acc = mfma16(Al[kt], bh_.v, acc);
        }
        const int c = ct * 16 + n16, hh = c >> 5, d = c & 31;
        const size_t base = ((size_t)(b * 4 + hh) * 512 + (rbl + row0 + quad * 4)) * 32 + d;
#pragma unroll
        for (int r = 0; r < 4; r++) {
            u16 hv = f2bf(acc[r]);
            khi[base + (size_t)r * 32] = hv;
            klo[base + (size_t)r * 32] = f2bf(acc[r] - bf2f(hv));
        }
    }

    // ---- V: kv cols 128..255 -> vT tiled [bh][n>>3][d][n&7] ----
#pragma unroll
    for (int ct = 0; ct < 8; ct++) {
        f32x4 acc = zero;
#pragma unroll
        for (int kt = 0; kt < 4; kt++) {
            U8 bh_, bl_;
            bh_.q = *(const uint4*)(WkvT_hi + (128 + ct * 16 + n16) * 128 + kt * 32 + quad * 8);
            bl_.q = *(const uint4*)(WkvT_lo + (128 + ct * 16 + n16) * 128 + kt * 32 + quad * 8);
            acc = mfma16(Ah[kt], bh_.v, acc);
            acc = mfma16(Ah[kt], bl_.v, acc);
            acc = mfma16(Al[kt], bh_.v, acc);
        }
        const int c = ct * 16 + n16, hh = c >> 5, d = c & 31;
        const int n0 = rbl + row0 + quad * 4;
        unsigned int w0 = (unsigned int)f2bf(acc[0]) | ((unsigned int)f2bf(acc[1]) << 16);
        unsigned int w1 = (unsigned int)f2bf(acc[2]) | ((unsigned int)f2bf(acc[3]) << 16);
        uint2 val = make_uint2(w0, w1);
        *(uint2*)(vT + (size_t)(b * 4 + hh) * 16384 + (size_t)(n0 >> 3) * 256 + d * 8 + (n0 & 7)) = val;
    }
}

// ---------------------------------------------------------------------------
// MFMA attention. vT tiled: [bh][node/8][d(32)][node%8]. (unchanged)
__global__ __launch_bounds__(256) void attn_mfma_kernel(const float* __restrict__ qbuf,
                                                        const u16* __restrict__ khi,
                                                        const u16* __restrict__ klo,
                                                        const u16* __restrict__ vT,
                                                        float* __restrict__ ao) {
    __shared__ u16 transit[8][16 * 36];
    const int t = threadIdx.x;
    const int w = t >> 6, L = t & 63;
    const int n16 = L & 15, quad = L >> 4;
    const int bh = blockIdx.y, b = bh >> 2, h = bh & 3;
    const int qbase = blockIdx.x * 128 + w * 32;

    bf16x8 qhi[2], qlo[2];
#pragma unroll
    for (int p = 0; p < 2; p++) {
        const float* qp = qbuf + (size_t)(b * 512 + qbase + p * 16 + n16) * 128 + h * 32 + quad * 8;
        U8 uh, ul;
#pragma unroll
        for (int j = 0; j < 8; j++) {
            float f = qp[j] * 0.17677669529663687f;
            u16 hi = f2bf(f);
            uh.s[j] = hi;
            ul.s[j] = f2bf(f - bf2f(hi));
        }
        qhi[p] = uh.v; qlo[p] = ul.v;
    }

    const f32x4 zero = {0.f, 0.f, 0.f, 0.f};

    float m[2][4];
#pragma unroll
    for (int p = 0; p < 2; p++)
#pragma unroll
        for (int r = 0; r < 4; r++) m[p][r] = -1e30f;

    for (int j0 = 0; j0 < 512; j0 += 16) {
        U8 ub; ub.q = *(const uint4*)(khi + (size_t)(bh * 512 + j0 + n16) * 32 + quad * 8);
#pragma unroll
        for (int p = 0; p < 2; p++) {
            f32x4 s = mfma16(qhi[p], ub.v, zero);
#pragma unroll
            for (int r = 0; r < 4; r++) m[p][r] = fmaxf(m[p][r], s[r]);
        }
    }
#pragma unroll
    for (int p = 0; p < 2; p++)
#pragma unroll
        for (int r = 0; r < 4; r++) {
            float mv = m[p][r];
#pragma unroll
            for (int mask = 1; mask < 16; mask <<= 1) mv = fmaxf(mv, __shfl_xor(mv, mask));
            m[p][r] = mv;
        }

    float l[2][4] = {{0.f, 0.f, 0.f, 0.f}, {0.f, 0.f, 0.f, 0.f}};
    f32x4 O[2][2];
#pragma unroll
    for (int p = 0; p < 2; p++)
#pragma unroll
        for (int dt = 0; dt < 2; dt++) O[p][dt] = zero;

    u16* tr[2] = { transit[w * 2 + 0], transit[w * 2 + 1] };

    for (int jb = 0; jb < 512; jb += 32) {
#pragma unroll
        for (int jt = 0; jt < 2; jt++) {
            const int j0 = jb + jt * 16;
            const size_t kidx = (size_t)(bh * 512 + j0 + n16) * 32 + quad * 8;
            U8 uh; uh.q = *(const uint4*)(khi + kidx);
            U8 ul; ul.q = *(const uint4*)(klo + kidx);
#pragma unroll
            for (int p = 0; p < 2; p++) {
                f32x4 s = mfma16(qhi[p], uh.v, zero);
                s = mfma16(qhi[p], ul.v, s);
                s = mfma16(qlo[p], uh.v, s);
#pragma unroll
                for (int r = 0; r < 4; r++) {
                    float pr = __expf(s[r] - m[p][r]);
                    u16 pb = f2bf(pr);
                    l[p][r] += bf2f(pb);
                    tr[p][(quad * 4 + r) * 36 + jt * 16 + n16] = pb;
                }
            }
        }
        bf16x8 A[2];
#pragma unroll
        for (int p = 0; p < 2; p++) {
            const u16* trp = tr[p];
            const int off = n16 * 36 + quad * 8;
            uint2 lo = *(const uint2*)(trp + off);
            uint2 hi2 = *(const uint2*)(trp + off + 4);
            U8 ua; ua.q = make_uint4(lo.x, lo.y, hi2.x, hi2.y);
            A[p] = ua.v;
        }
#pragma unroll
        for (int dt = 0; dt < 2; dt++) {
            U8 uv; uv.q = *(const uint4*)(vT + (size_t)bh * 16384
                                          + (size_t)((jb + quad * 8) >> 3) * 256
                                          + (size_t)(dt * 16 + n16) * 8);
#pragma unroll
            for (int p = 0; p < 2; p++) O[p][dt] = mfma16(A[p], uv.v, O[p][dt]);
        }
    }

#pragma unroll
    for (int p = 0; p < 2; p++)
#pragma unroll
        for (int r = 0; r < 4; r++) {
            float lv = l[p][r];
#pragma unroll
            for (int mask = 1; mask < 16; mask <<= 1) lv += __shfl_xor(lv, mask);
            float inv = 1.0f / lv;
#pragma unroll
            for (int dt = 0; dt < 2; dt++)
                ao[(size_t)(b * 512 + qbase + p * 16 + quad * 4 + r) * 128 + h * 32 + dt * 16 + n16]
                    = O[p][dt][r] * inv;
        }
}

// ---------------------------------------------------------------------------
extern "C" void kernel_launch(void* const* d_in, const int* in_sizes, int n_in,
                              void* d_out, int out_size, void* d_ws, size_t ws_size,
                              hipStream_t stream) {
    const float* x    = (const float*)d_in[0];
    const int*   ei   = (const int*)d_in[1];
    const float* ee   = (const float*)d_in[2];
    // d_in[3] = batch (unused; uniform graphs)
    const float* Wg   = (const float*)d_in[4];
    const float* bg   = (const float*)d_in[5];
    const float* root = (const float*)d_in[6];
    const float* Wq   = (const float*)d_in[7];
    const float* Wkv  = (const float*)d_in[8];
    const float* Wo   = (const float*)d_in[9];
    const float* bo   = (const float*)d_in[10];

    // Workspace layout (67.4 MB known-good):
    //   [0,128K)        degf (fp32 deg per node)
    //   [128K,256K)     dinv
    //   [256K,16M+256K) buf1: h0 -> q -> attn_out
    //   next 16M        hbuf: h
    //   next 32M+320K   reg3: offs(128K)+pairs@256K(4M) (dead after gather) -> khi(8M)+klo(8M);
    //                   wt arena (320K) at reg3+16M
    char* ws = (char*)d_ws;
    float* degf    = (float*)ws;
    float* dinv    = (float*)(ws + 131072);
    float* buf1    = (float*)(ws + 262144);
    float* hbuf    = buf1 + 4194304;
    char*  reg3    = (char*)(hbuf + 4194304);
    u16*   khi     = (u16*)reg3;                     // written by qkv (after gather)
    u16*   klo     = khi + 4194304;
    u16*   wt      = (u16*)(reg3 + 16777216);        // 320 KB WT hi/lo arena
    u16*   vT      = (u16*)d_out;                    // scratch; overwritten by final gemm
    int*   offs    = (int*)reg3;                     // CSR scratch (dead after gather)
    int2*  pairs   = (int2*)(reg3 + 262144);         // 4 MB, int2-aligned

    // setup: per-graph CSR (blocks 0-63) + weight prep (blocks 64-127)
    setup_kernel<<<128, 512, 0, stream>>>(ei, Wg, Wq, Wkv, Wo, wt, dinv, degf, offs, pairs);

    // h0 = x @ W_gcn + b_gcn   (MFMA split-bf16)
    mgemm_kernel<<<512, 256, 0, stream>>>(x, wt, wt + 16384, bg, buf1);

    // h = CSR gather + self term
    gather_kernel<<<32768, 128, 0, stream>>>(pairs, offs, degf, dinv, buf1, ee, root, hbuf);

    // fused MFMA: q = h@Wq -> buf1 ; k/v = h@Wkv -> khi/klo/vT (bf16)
    qkv_mfma_kernel<<<512, 256, 0, stream>>>(hbuf, wt, buf1, khi, klo, vT);

    // MFMA attention -> buf1 (aliases q; per-block disjoint read/write regions)
    attn_mfma_kernel<<<dim3(4, 256), 256, 0, stream>>>(buf1, khi, klo, vT, buf1);

    // out = attn_out @ Wout + b_out   (MFMA split-bf16)
    mgemm_kernel<<<512, 256, 0, stream>>>(buf1, wt + 131072, wt + 147456, bo, (float*)d_out);
}